// Round 3
// baseline (903.715 us; speedup 1.0000x reference)
//
#include <hip/hip_runtime.h>

// Maxish: x [B,T,X,N=256] f32, scale scalar f32 -> out [B,T,X] f32.
// rho_max = max_n x ; rt = (x - rho_max)/(rho_max + 1e-8)
// pos = rho_max * sum(exp((s+1)*rt)) / sum(exp(s*rt))   [softmax shift = 0 exactly, since max(rt)=0]
// neg = rho_max                                          [softmax sums to 1]
// out = rm>0 ? pos : (rm<0 ? neg : 0)
//
// DIAGNOSTIC BUILD: REPS=4 identical full passes (idempotent output) so this
// kernel exceeds the ~333us harness fill dispatches and surfaces its own
// rocprof counters (hbm_gbps / FETCH_SIZE / VALUBusy). True per-pass time = dur/4.

#define SMALL_NUMBER 1e-8f
#define NCOL 256
#define REPS 4

typedef float f32x4 __attribute__((ext_vector_type(4)));

__global__ __launch_bounds__(256, 8) void maxish_kernel(
    const float* __restrict__ x,
    const float* __restrict__ scale_p,
    float* __restrict__ out,
    int rows)
{
    const float s = scale_p[0];           // wave-uniform scalar
    const int lane  = threadIdx.x & 63;
    const int sub   = lane & 15;          // lane within 16-lane row-group
    const int grp   = lane >> 4;          // which of the 4 rows this wave handles
    const int wib   = threadIdx.x >> 6;
    const int wpb   = blockDim.x >> 6;
    const int gwave = blockIdx.x * wpb + wib;
    const int nwav  = gridDim.x * wpb;

    for (int rep = 0; rep < REPS; ++rep) {
        // compile-time memory barrier: forces re-load of x each pass (no CSE
        // across reps). No runtime cost, no effect on graph capture.
        asm volatile("" ::: "memory");

        for (int r4 = gwave; r4 * 4 < rows; r4 += nwav) {
            const int row = r4 * 4 + grp;
            if (row >= rows) break;
            const f32x4* p = reinterpret_cast<const f32x4*>(x + (size_t)row * NCOL);

            // lane covers cols {k*64 + sub*4 .. +3}, k=0..3 -> each load instr
            // covers 4x256B contiguous segments (fully coalesced). Nontemporal:
            // pure streaming, no reuse -> don't pollute L2/L3.
            f32x4 v0 = __builtin_nontemporal_load(p +  0 + sub);
            f32x4 v1 = __builtin_nontemporal_load(p + 16 + sub);
            f32x4 v2 = __builtin_nontemporal_load(p + 32 + sub);
            f32x4 v3 = __builtin_nontemporal_load(p + 48 + sub);

            // ---- row max (16-lane butterfly) ----
            float mx = fmaxf(fmaxf(fmaxf(v0[0], v0[1]), fmaxf(v0[2], v0[3])),
                       fmaxf(fmaxf(fmaxf(v1[0], v1[1]), fmaxf(v1[2], v1[3])),
                       fmaxf(fmaxf(fmaxf(v2[0], v2[1]), fmaxf(v2[2], v2[3])),
                             fmaxf(fmaxf(v3[0], v3[1]), fmaxf(v3[2], v3[3])))));
            #pragma unroll
            for (int off = 8; off >= 1; off >>= 1)
                mx = fmaxf(mx, __shfl_xor(mx, off, 16));

            const float inv = 1.0f / (mx + SMALL_NUMBER);
            const float ca  = s * inv;            // exp(s*rt)     = exp((xv-mx)*ca)
            const float cb  = (s + 1.0f) * inv;   // exp((s+1)*rt) = exp((xv-mx)*cb)

            // ---- fused pos-branch sums: num = sum exp((s+1)rt), den = sum exp(s*rt) ----
            float num = 0.0f, den = 0.0f;
            auto proc = [&](float xv) {
                float t = xv - mx;
                den += __expf(t * ca);
                num += __expf(t * cb);
            };
            proc(v0[0]); proc(v0[1]); proc(v0[2]); proc(v0[3]);
            proc(v1[0]); proc(v1[1]); proc(v1[2]); proc(v1[3]);
            proc(v2[0]); proc(v2[1]); proc(v2[2]); proc(v2[3]);
            proc(v3[0]); proc(v3[1]); proc(v3[2]); proc(v3[3]);

            #pragma unroll
            for (int off = 8; off >= 1; off >>= 1) {
                num += __shfl_xor(num, off, 16);
                den += __shfl_xor(den, off, 16);
            }

            // ---- branch select ----
            float res;
            if (mx > 0.0f)      res = mx * (num / den);
            else if (mx < 0.0f) res = mx;   // softmax sums to 1 -> rho_max exactly
            else                res = 0.0f;

            if (sub == 0) out[row] = res;   // 4 consecutive floats per wave
        }
    }
}

extern "C" void kernel_launch(void* const* d_in, const int* in_sizes, int n_in,
                              void* d_out, int out_size, void* d_ws, size_t ws_size,
                              hipStream_t stream) {
    const float* x     = (const float*)d_in[0];
    const float* scale = (const float*)d_in[1];
    float* out         = (float*)d_out;

    const int rows = in_sizes[0] / NCOL;   // B*T*X = 524288

    const int block = 256;                 // 4 waves/block
    int grid = 2048;                       // 8 blocks/CU -> 32 waves/CU, grid-stride
    int need = (rows + 15) / 16;           // 4 rows per wave-iter, 4 waves/block
    if (grid > need) grid = need;

    maxish_kernel<<<grid, block, 0, stream>>>(x, scale, out, rows);
}